// Round 4
// baseline (350.640 us; speedup 1.0000x reference)
//
#include <hip/hip_runtime.h>
#include <math.h>

#define NEL 10
#define FD 64
#define NBES 8
#define GG 20
#define HML 16
#define EGB 128   // edge_geom blocks (pol partials sized to this)

typedef __attribute__((ext_vector_type(8))) short short8;
typedef __attribute__((ext_vector_type(4))) float f32x4;

__device__ __forceinline__ float wred(float v) {
    #pragma unroll
    for (int off = 32; off > 0; off >>= 1) v += __shfl_down(v, off, 64);
    return v;
}

__device__ __forceinline__ float silu(float h) {
    return h / (1.f + __expf(-h));
}

__device__ __forceinline__ unsigned short f2bf(float x) {
    unsigned int b = __float_as_uint(x);
    unsigned int r = (b + 0x7FFFu + ((b >> 16) & 1u)) >> 16;
    return (unsigned short)r;
}

// Per-node setup: species, E0, formal charge.
__global__ __launch_bounds__(256) void setup_nodes_k(
    const float* __restrict__ attrs, const float* __restrict__ ae,
    const float* __restrict__ fc, int* __restrict__ spec,
    float* __restrict__ q, float* __restrict__ out_nodeE, int N_)
{
    int n = blockIdx.x * 256 + threadIdx.x;
    if (n < N_) {
        const float* row = attrs + (size_t)n * NEL;
        int sp = 0;
        #pragma unroll
        for (int i = 0; i < NEL; ++i) if (row[i] > 0.5f) sp = i;
        spec[n] = sp;
        out_nodeE[n] = ae[sp];
        q[n] = fc[sp];
    }
}

__global__ __launch_bounds__(256) void init_scal_k(
    float* __restrict__ scal, const float* __restrict__ embed_w,
    const int* __restrict__ spec, int N_)
{
    int idx = blockIdx.x * 256 + threadIdx.x;
    if (idx < N_ * FD) {
        int n = idx >> 6, f = idx & 63;
        scal[idx] = embed_w[spec[n] * FD + f];
    }
}

// ---- counting sort of edges by receiver ----
__global__ __launch_bounds__(256) void hist_k(
    const int* __restrict__ eidx, int* __restrict__ cnt, int E_)
{
    int e = blockIdx.x * 256 + threadIdx.x;
    if (e < E_) atomicAdd(&cnt[eidx[E_ + e]], 1);
}

__global__ __launch_bounds__(1024) void scan_k(
    const int* __restrict__ cnt, int* __restrict__ cur, int N_)
{
    __shared__ int ps[1024];
    int t = threadIdx.x;
    int base = t * 20;
    int s = 0;
    #pragma unroll 4
    for (int i = 0; i < 20; ++i) { int idx = base + i; if (idx < N_) s += cnt[idx]; }
    ps[t] = s;
    __syncthreads();
    for (int off = 1; off < 1024; off <<= 1) {
        int v = (t >= off) ? ps[t - off] : 0;
        __syncthreads();
        ps[t] += v;
        __syncthreads();
    }
    int ex = (t == 0) ? 0 : ps[t - 1];
    for (int i = 0; i < 20; ++i) {
        int idx = base + i;
        if (idx < N_) { cur[idx] = ex; ex += cnt[idx]; }
    }
}

__global__ __launch_bounds__(256) void scatter_k(
    const int* __restrict__ eidx, int* __restrict__ cur,
    int* __restrict__ snd_s, int* __restrict__ rcv_s, int E_)
{
    int e = blockIdx.x * 256 + threadIdx.x;
    if (e < E_) {
        int r = eidx[E_ + e];
        int p = atomicAdd(&cur[r], 1);
        snd_s[p] = eidx[e];
        rcv_s[p] = r;
    }
}

// Edge geometry over SORTED edges: bessel basis (coalesced writes), flux, pol partials.
__global__ __launch_bounds__(256) void edge_geom_k(
    const float* __restrict__ pos, const int* __restrict__ snd_s,
    const int* __restrict__ rcv_s, const float* __restrict__ flux_w,
    float* __restrict__ ef, float* __restrict__ polpart, int E_, int ng)
{
    __shared__ float lpol[GG][3];
    int tid = threadIdx.x;
    if (tid < GG) { lpol[tid][0] = 0.f; lpol[tid][1] = 0.f; lpol[tid][2] = 0.f; }
    __syncthreads();
    float fw[NBES];
    #pragma unroll
    for (int i = 0; i < NBES; ++i) fw[i] = flux_w[i] + flux_w[NBES + i];
    const float PI = 3.14159265358979323846f;
    for (int p = blockIdx.x * 256 + tid; p < E_; p += EGB * 256) {
        int s = snd_s[p], r = rcv_s[p];
        float dx = pos[(size_t)r*3+0] - pos[(size_t)s*3+0];
        float dy = pos[(size_t)r*3+1] - pos[(size_t)s*3+1];
        float dz = pos[(size_t)r*3+2] - pos[(size_t)s*3+2];
        float len = sqrtf(dx*dx + dy*dy + dz*dz + 1e-12f);
        float x = len * 0.2f;
        float u = 0.f;
        if (x < 1.f) {
            float x2 = x * x;
            float x5 = x2 * x2 * x;
            u = 1.f - 21.f * x5 + 35.f * x5 * x - 15.f * x5 * x2;
        }
        float pref = 0.6324555320336759f / len * u;   // sqrt(2/5)/r * u
        float theta = PI * x;
        float s1, c1;
        __sincosf(theta, &s1, &c1);
        float c2 = 2.f * c1;
        float sp_ = 0.f, sn = s1;
        float flux = 0.f;
        float* efe = ef + (size_t)p * NBES;
        #pragma unroll
        for (int i = 0; i < NBES; ++i) {
            float rb = pref * sn;
            efe[i] = rb;
            flux += rb * fw[i];
            float nx = c2 * sn - sp_;
            sp_ = sn; sn = nx;
        }
        int g = r / ng;
        atomicAdd(&lpol[g][0], flux * dx);
        atomicAdd(&lpol[g][1], flux * dy);
        atomicAdd(&lpol[g][2], flux * dz);
    }
    __syncthreads();
    if (tid < GG * 3) polpart[blockIdx.x * (GG * 3) + tid] = lpol[tid / 3][tid % 3];
}

// Radial MLP + message + segmented scatter over receiver-sorted edges.
// Phase 1: h = silu(ef@W1+b1) -> LDS bf16. Phase 2: A = h@W2 via MFMA.
// Epilogue: C -> LDS, per-wave running-sum over sorted positions, one atomic per segment.
__global__ __launch_bounds__(256) void edge_mlp_k(
    const float* __restrict__ ef, const int* __restrict__ snd_s,
    const int* __restrict__ rcv_s,
    const float* __restrict__ w1, const float* __restrict__ b1,
    const float* __restrict__ w2, const float* __restrict__ scal,
    float* __restrict__ agg0, int layer, int E_)
{
    __shared__ __align__(16) char smem[18432];     // hsh(9216)+w2t(9216), aliased by ctile(16640)
    __shared__ float w1b[8 * 64 + 64];
    __shared__ int sndl[64], rcvl[64];
    unsigned short* hsh = (unsigned short*)smem;           // stride 72 shorts
    unsigned short* w2t = (unsigned short*)(smem + 9216);  // stride 72 shorts

    int t = threadIdx.x;
    int ebase = blockIdx.x * 64;

    if (t < 64) {
        sndl[t] = snd_s[ebase + t];
        rcvl[t] = rcv_s[ebase + t];
        w1b[512 + t] = b1[layer * FD + t];
    }
    for (int i = t; i < 512; i += 256) w1b[i] = w1[layer * 512 + i];
    #pragma unroll
    for (int i = 0; i < 16; ++i) {
        int linear = i * 256 + t;              // = k*64 + f
        int k = linear >> 6, f = linear & 63;
        w2t[f * 72 + k] = f2bf(w2[layer * 4096 + linear]);
    }
    __syncthreads();

    // phase 1: thread -> edge e = t&63, k-range kb..kb+15 (ef is sorted: coalesced)
    {
        int e = t & 63, kb = (t >> 6) * 16;
        const f32x4* e4 = (const f32x4*)(ef + (size_t)(ebase + e) * NBES);
        f32x4 A0 = e4[0], A1 = e4[1];
        float efr[8] = {A0.x, A0.y, A0.z, A0.w, A1.x, A1.y, A1.z, A1.w};
        unsigned int hv[8];
        #pragma unroll
        for (int jp = 0; jp < 8; ++jp) {
            unsigned int pk = 0;
            #pragma unroll
            for (int half = 0; half < 2; ++half) {
                int k = kb + jp * 2 + half;
                float h = w1b[512 + k];
                #pragma unroll
                for (int i = 0; i < 8; ++i) h += efr[i] * w1b[i * 64 + k];
                pk |= ((unsigned int)f2bf(silu(h))) << (16 * half);
            }
            hv[jp] = pk;
        }
        uint4* dst = (uint4*)&hsh[e * 72 + kb];
        dst[0] = make_uint4(hv[0], hv[1], hv[2], hv[3]);
        dst[1] = make_uint4(hv[4], hv[5], hv[6], hv[7]);
    }
    __syncthreads();

    // phase 2: wave w -> edge rows 16w..16w+15, all 4 feature tiles
    int w = t >> 6, lane = t & 63;
    int mrow = lane & 15, quad = lane >> 4;
    short8 a0 = *(const short8*)&hsh[(16 * w + mrow) * 72 + quad * 8];
    short8 a1 = *(const short8*)&hsh[(16 * w + mrow) * 72 + 32 + quad * 8];
    f32x4 c[4];
    #pragma unroll
    for (int nt = 0; nt < 4; ++nt) {
        short8 b0 = *(const short8*)&w2t[(nt * 16 + mrow) * 72 + quad * 8];
        short8 bv = *(const short8*)&w2t[(nt * 16 + mrow) * 72 + 32 + quad * 8];
        f32x4 cc = {0.f, 0.f, 0.f, 0.f};
        cc = __builtin_amdgcn_mfma_f32_16x16x32_bf16(a0, b0, cc, 0, 0, 0);
        cc = __builtin_amdgcn_mfma_f32_16x16x32_bf16(a1, bv, cc, 0, 0, 0);
        c[nt] = cc;
    }
    __syncthreads();                                // hsh/w2t dead; alias as ctile
    float* ctile = (float*)smem;                    // 64 x 65
    #pragma unroll
    for (int nt = 0; nt < 4; ++nt)
        #pragma unroll
        for (int reg = 0; reg < 4; ++reg)
            ctile[(16 * w + quad * 4 + reg) * 65 + nt * 16 + mrow] = c[nt][reg];
    __syncthreads();

    // epilogue: wave w reduces sorted positions [16w,16w+16); receiver id wave-uniform
    int f = lane;
    int p0 = w * 16;
    int curR = rcvl[p0];
    float run = 0.f;
    #pragma unroll
    for (int pp = 0; pp < 16; ++pp) {
        int p = p0 + pp;
        int r = rcvl[p];
        float v = ctile[p * 65 + f] * scal[(size_t)sndl[p] * FD + f];
        if (r != curR) {
            atomicAdd(&agg0[(size_t)curR * FD + f], run);
            run = v; curR = r;
        } else {
            run += v;
        }
    }
    atomicAdd(&agg0[(size_t)curR * FD + f], run);
}

// Node update: scalars' = agg/16 + (agg/16)^2 + scal*prod_w[spec]; per-node energies to scratch.
__global__ __launch_bounds__(256) void node_update_k(
    float* __restrict__ scal, float* __restrict__ agg0,
    const int* __restrict__ spec, const float* __restrict__ prod_w,
    const float* __restrict__ readout_w, const float* __restrict__ ro2_w1,
    const float* __restrict__ ro2_b1, const float* __restrict__ ro2_w2,
    const float* __restrict__ charge_w, float* __restrict__ q,
    float* __restrict__ out_nodeE, float* __restrict__ nEl,
    int layer, int last, int N_)
{
    __shared__ float vsh[4][FD];
    int wid = threadIdx.x >> 6, lane = threadIdx.x & 63;
    int n = blockIdx.x * 4 + wid;
    int sp = spec[n];
    size_t idx = (size_t)n * FD + lane;
    float a = agg0[idx] * 0.0625f;
    agg0[idx] = 0.f;                       // pre-zero for next layer
    float v = a + a * a + scal[idx] * prod_w[(layer * NEL + sp) * FD + lane];
    scal[idx] = v;

    float ne;
    if (!last) {
        ne = wred(v * readout_w[layer * FD + lane]);
    } else {
        vsh[wid][lane] = v;
        __syncthreads();
        float h = 0.f;
        if (lane < HML) {
            h = ro2_b1[lane];
            for (int ff = 0; ff < FD; ++ff) h += vsh[wid][ff] * ro2_w1[ff * HML + lane];
            h = silu(h) * ro2_w2[lane];
        }
        ne = wred(h);
    }
    float qs = wred(v * charge_w[layer * FD + lane]);
    if (lane == 0) {
        nEl[n] = ne;
        out_nodeE[n] += ne;
        q[n] += qs;
    }
}

// Per-graph reductions: one block per graph, zero contention.
__global__ __launch_bounds__(256) void graph_sum_k(
    const int* __restrict__ spec, const float* __restrict__ ae,
    const float* __restrict__ fc, const float* __restrict__ pos,
    const float* __restrict__ q, const float* __restrict__ nE0,
    const float* __restrict__ nE1, const float* __restrict__ polpart,
    float* __restrict__ acc, int ng)
{
    __shared__ float red[4][8];
    int g = blockIdx.x;
    int tid = threadIdx.x, wid = tid >> 6, lane = tid & 63;
    float se0 = 0.f, s0 = 0.f, s1 = 0.f, sq = 0.f, p0 = 0.f, p1 = 0.f, p2 = 0.f;
    for (int n = g * ng + tid; n < (g + 1) * ng; n += 256) {
        int sp = spec[n];
        float fq = fc[sp];
        se0 += ae[sp];
        s0 += nE0[n];
        s1 += nE1[n];
        sq += q[n];
        p0 += fq * pos[(size_t)n*3+0];
        p1 += fq * pos[(size_t)n*3+1];
        p2 += fq * pos[(size_t)n*3+2];
    }
    float vals[7] = {se0, s0, s1, sq, p0, p1, p2};
    #pragma unroll
    for (int k = 0; k < 7; ++k) {
        float r = wred(vals[k]);
        if (lane == 0) red[wid][k] = r;
    }
    __syncthreads();
    if (tid < 7) {
        float s = red[0][tid] + red[1][tid] + red[2][tid] + red[3][tid];
        if (tid == 0) acc[0 + g] = s;
        else if (tid == 1) acc[20 + g] = s;
        else if (tid == 2) acc[40 + g] = s;
        else if (tid == 3) acc[140 + g] = s;
        else {
            int cdim = tid - 4;
            for (int b = 0; b < EGB; ++b) s += polpart[b * (GG * 3) + g * 3 + cdim];
            acc[80 + g * 3 + cdim] = s;
        }
    }
}

// Direct screened Coulomb, i<j symmetry. Block = (graph, 64-wide i-chunk).
__global__ __launch_bounds__(256) void coulomb_k(
    const float* __restrict__ q, const float* __restrict__ pos,
    float* __restrict__ eel, int ng)
{
    __shared__ float qs[1024], px[1024], py[1024], pz[1024];
    __shared__ float wsum[4];
    int g = blockIdx.x >> 4, chunk = blockIdx.x & 15;
    int tid = threadIdx.x;
    const float* qg = q + (size_t)g * ng;
    const float* pg = pos + (size_t)g * ng * 3;
    for (int i = tid; i < ng; i += 256) {
        qs[i] = qg[i];
        px[i] = pg[(size_t)i*3+0]; py[i] = pg[(size_t)i*3+1]; pz[i] = pg[(size_t)i*3+2];
    }
    __syncthreads();
    int il = tid & 63;
    int i = chunk * 64 + il;
    int wj = tid >> 6;
    float acc = 0.f;
    if (i < ng) {
        float qi = qs[i], xi = px[i], yi = py[i], zi = pz[i];
        for (int j = chunk * 64 + wj; j < ng; j += 4) {   // j wave-uniform; only j>i pairs
            if (j > i) {
                float dx = xi - px[j], dy = yi - py[j], dz = zi - pz[j];
                float d2 = dx*dx + dy*dy + dz*dz + 1e-12f;
                float rinv = __frsqrt_rn(d2);
                float r = d2 * rinv;
                float x = 0.5f * r;
                float tt = __frcp_rn(1.f + 0.3275911f * x);
                float poly = ((((1.061405429f*tt - 1.453152027f)*tt + 1.421413741f)*tt
                               - 0.284496736f)*tt + 0.254829592f)*tt;
                float erfv = 1.f - poly * __expf(-x * x);
                acc += qi * qs[j] * erfv * rinv;
            }
        }
    }
    acc = wred(acc);
    if ((tid & 63) == 0) wsum[tid >> 6] = acc;
    __syncthreads();
    if (tid == 0) atomicAdd(&eel[g], wsum[0] + wsum[1] + wsum[2] + wsum[3]);
}

__global__ void finalize_k(const float* __restrict__ acc, float* __restrict__ out,
                           int G_, int N_)
{
    int g = threadIdx.x;
    if (g < G_) {
        float a0 = acc[0 + g], a1 = acc[20 + g], a2 = acc[40 + g], ee = acc[60 + g];
        out[g] = a0 + a1 + a2 + ee;                 // total_energy
        float* contrib = out + G_ + N_;             // contributions [G,3]
        contrib[g*3+0] = a0; contrib[g*3+1] = a1; contrib[g*3+2] = a2;
        float* pol = contrib + G_ * 3;              // pol [G,3]
        pol[g*3+0] = acc[80 + g*3+0];
        pol[g*3+1] = acc[80 + g*3+1];
        pol[g*3+2] = acc[80 + g*3+2];
        float* qt = pol + G_ * 3;                   // total_charge [G]
        qt[g] = acc[140 + g];
    }
}

extern "C" void kernel_launch(void* const* d_in, const int* in_sizes, int n_in,
                              void* d_out, int out_size, void* d_ws, size_t ws_size,
                              hipStream_t stream)
{
    const float* node_attrs      = (const float*)d_in[0];
    const float* positions       = (const float*)d_in[1];
    const int*   edge_index      = (const int*)d_in[2];
    const float* atomic_energies = (const float*)d_in[5];
    const float* embed_w         = (const float*)d_in[6];
    const float* radial_w1       = (const float*)d_in[7];
    const float* radial_b1       = (const float*)d_in[8];
    const float* radial_w2       = (const float*)d_in[9];
    const float* prod_w          = (const float*)d_in[10];
    const float* readout_w       = (const float*)d_in[11];
    const float* ro2_w1          = (const float*)d_in[12];
    const float* ro2_b1          = (const float*)d_in[13];
    const float* ro2_w2          = (const float*)d_in[14];
    const float* charge_w        = (const float*)d_in[15];
    const float* flux_w          = (const float*)d_in[16];
    const float* formal_charges  = (const float*)d_in[17];

    int N = in_sizes[0] / NEL;     // 20000
    int E = in_sizes[2] / 2;       // 320000
    const int G_ = GG;             // 20
    int ng = N / G_;               // 1000

    float* ws      = (float*)d_ws;
    float* scal    = ws;                               // [N,64]
    float* agg0    = scal + (size_t)N * FD;            // [N,64]
    float* ef      = agg0 + (size_t)N * FD;            // [E,8] (sorted order)
    float* q       = ef + (size_t)E * NBES;            // [N]
    int*   spec    = (int*)(q + N);                    // [N]
    float* nE0     = (float*)(spec + N);               // [N]
    float* nE1     = nE0 + N;                          // [N]
    float* polpart = nE1 + N;                          // [EGB*60]
    float* acc     = polpart + EGB * (GG * 3);         // [160]
    int*   cnt     = (int*)(acc + 160);                // [N]
    int*   cur     = cnt + N;                          // [N]
    int*   snd_s   = cur + N;                          // [E]
    int*   rcv_s   = snd_s + E;                        // [E]

    float* out = (float*)d_out;
    float* out_nodeE = out + G_;

    hipMemsetAsync(agg0, 0, (size_t)N * FD * sizeof(float), stream);
    hipMemsetAsync(acc, 0, 160 * sizeof(float), stream);
    hipMemsetAsync(cnt, 0, (size_t)N * sizeof(int), stream);

    setup_nodes_k<<<(N + 255) / 256, 256, 0, stream>>>(
        node_attrs, atomic_energies, formal_charges, spec, q, out_nodeE, N);
    init_scal_k<<<(N * FD + 255) / 256, 256, 0, stream>>>(scal, embed_w, spec, N);

    hist_k<<<(E + 255) / 256, 256, 0, stream>>>(edge_index, cnt, E);
    scan_k<<<1, 1024, 0, stream>>>(cnt, cur, N);
    scatter_k<<<(E + 255) / 256, 256, 0, stream>>>(edge_index, cur, snd_s, rcv_s, E);

    edge_geom_k<<<EGB, 256, 0, stream>>>(positions, snd_s, rcv_s, flux_w, ef, polpart, E, ng);

    for (int l = 0; l < 2; ++l) {
        edge_mlp_k<<<E / 64, 256, 0, stream>>>(
            ef, snd_s, rcv_s, radial_w1, radial_b1, radial_w2, scal, agg0, l, E);
        node_update_k<<<N / 4, 256, 0, stream>>>(
            scal, agg0, spec, prod_w, readout_w, ro2_w1, ro2_b1, ro2_w2,
            charge_w, q, out_nodeE, (l == 0) ? nE0 : nE1,
            l, (l == 1) ? 1 : 0, N);
    }

    graph_sum_k<<<G_, 256, 0, stream>>>(spec, atomic_energies, formal_charges,
                                        positions, q, nE0, nE1, polpart, acc, ng);
    coulomb_k<<<G_ * 16, 256, 0, stream>>>(q, positions, acc + 60, ng);
    finalize_k<<<1, 64, 0, stream>>>(acc, out, G_, N);
}

// Round 5
// 315.765 us; speedup vs baseline: 1.1104x; 1.1104x over previous
//
#include <hip/hip_runtime.h>
#include <math.h>

#define NEL 10
#define FD 64
#define NBES 8
#define GG 20
#define HML 16
#define EGB 128   // edge_geom blocks (pol partials sized to this)

typedef __attribute__((ext_vector_type(8))) short short8;
typedef __attribute__((ext_vector_type(4))) float f32x4;

__device__ __forceinline__ float wred(float v) {
    #pragma unroll
    for (int off = 32; off > 0; off >>= 1) v += __shfl_down(v, off, 64);
    return v;
}

__device__ __forceinline__ float silu(float h) {
    return h / (1.f + __expf(-h));
}

__device__ __forceinline__ unsigned short f2bf(float x) {
    unsigned int b = __float_as_uint(x);
    unsigned int r = (b + 0x7FFFu + ((b >> 16) & 1u)) >> 16;
    return (unsigned short)r;
}

// Fused: species via ballot (wave == node), scal init, E0/charge, edge histogram.
__global__ __launch_bounds__(256) void setup_k(
    const float* __restrict__ attrs, const float* __restrict__ ae,
    const float* __restrict__ fc, const float* __restrict__ embed_w,
    const int* __restrict__ eidx, int* __restrict__ spec,
    float* __restrict__ q, float* __restrict__ out_nodeE,
    float* __restrict__ scal, int* __restrict__ cnt, int N_, int E_)
{
    int idx = blockIdx.x * 256 + threadIdx.x;   // grid = N*64 threads; wave = one node
    int lane = threadIdx.x & 63;
    int n = idx >> 6;
    bool pred = (lane < NEL) && (attrs[(size_t)n * NEL + lane] > 0.5f);
    unsigned long long m = __ballot(pred);
    int sp = (int)__builtin_ctzll(m);
    scal[idx] = embed_w[sp * FD + lane];
    if (lane == 0) { spec[n] = sp; q[n] = fc[sp]; out_nodeE[n] = ae[sp]; }
    if (idx < E_) atomicAdd(&cnt[eidx[E_ + idx]], 1);
}

// Shuffle-based single-block scan (exclusive prefix over 20000 counts).
__global__ __launch_bounds__(1024) void scan_k(
    const int* __restrict__ cnt, int* __restrict__ cur, int N_)
{
    __shared__ int wtot[16];
    int t = threadIdx.x, lane = t & 63, wid = t >> 6;
    int base = t * 20;
    int c[20]; int s = 0;
    #pragma unroll
    for (int i = 0; i < 20; ++i) { int idx = base + i; c[i] = (idx < N_) ? cnt[idx] : 0; s += c[i]; }
    int v = s;
    #pragma unroll
    for (int off = 1; off < 64; off <<= 1) {
        int u = __shfl_up(v, off, 64);
        if (lane >= off) v += u;
    }
    if (lane == 63) wtot[wid] = v;
    __syncthreads();
    if (wid == 0 && lane < 16) {
        int wv = wtot[lane];
        #pragma unroll
        for (int off = 1; off < 16; off <<= 1) {
            int u = __shfl_up(wv, off, 64);
            if (lane >= off) wv += u;
        }
        wtot[lane] = wv;   // inclusive wave totals
    }
    __syncthreads();
    int ex = (wid > 0 ? wtot[wid - 1] : 0) + (v - s);
    #pragma unroll
    for (int i = 0; i < 20; ++i) {
        int idx = base + i;
        if (idx < N_) { cur[idx] = ex; ex += c[i]; }
    }
}

__global__ __launch_bounds__(256) void scatter_k(
    const int* __restrict__ eidx, int* __restrict__ cur,
    int* __restrict__ snd_s, int* __restrict__ rcv_s, int E_)
{
    int e = blockIdx.x * 256 + threadIdx.x;
    if (e < E_) {
        int r = eidx[E_ + e];
        int p = atomicAdd(&cur[r], 1);
        snd_s[p] = eidx[e];
        rcv_s[p] = r;
    }
}

// Edge geometry over SORTED edges: bessel basis (coalesced writes), flux, pol partials.
__global__ __launch_bounds__(256) void edge_geom_k(
    const float* __restrict__ pos, const int* __restrict__ snd_s,
    const int* __restrict__ rcv_s, const float* __restrict__ flux_w,
    float* __restrict__ ef, float* __restrict__ polpart, int E_, int ng)
{
    __shared__ float lpol[GG][3];
    int tid = threadIdx.x;
    if (tid < GG) { lpol[tid][0] = 0.f; lpol[tid][1] = 0.f; lpol[tid][2] = 0.f; }
    __syncthreads();
    float fw[NBES];
    #pragma unroll
    for (int i = 0; i < NBES; ++i) fw[i] = flux_w[i] + flux_w[NBES + i];
    const float PI = 3.14159265358979323846f;
    for (int p = blockIdx.x * 256 + tid; p < E_; p += EGB * 256) {
        int s = snd_s[p], r = rcv_s[p];
        float dx = pos[(size_t)r*3+0] - pos[(size_t)s*3+0];
        float dy = pos[(size_t)r*3+1] - pos[(size_t)s*3+1];
        float dz = pos[(size_t)r*3+2] - pos[(size_t)s*3+2];
        float len = sqrtf(dx*dx + dy*dy + dz*dz + 1e-12f);
        float x = len * 0.2f;
        float u = 0.f;
        if (x < 1.f) {
            float x2 = x * x;
            float x5 = x2 * x2 * x;
            u = 1.f - 21.f * x5 + 35.f * x5 * x - 15.f * x5 * x2;
        }
        float pref = 0.6324555320336759f / len * u;   // sqrt(2/5)/r * u
        float theta = PI * x;
        float s1, c1;
        __sincosf(theta, &s1, &c1);
        float c2 = 2.f * c1;
        float sp_ = 0.f, sn = s1;
        float flux = 0.f;
        float* efe = ef + (size_t)p * NBES;
        #pragma unroll
        for (int i = 0; i < NBES; ++i) {
            float rb = pref * sn;
            efe[i] = rb;
            flux += rb * fw[i];
            float nx = c2 * sn - sp_;
            sp_ = sn; sn = nx;
        }
        int g = r / ng;
        atomicAdd(&lpol[g][0], flux * dx);
        atomicAdd(&lpol[g][1], flux * dy);
        atomicAdd(&lpol[g][2], flux * dz);
    }
    __syncthreads();
    if (tid < GG * 3) polpart[blockIdx.x * (GG * 3) + tid] = lpol[tid / 3][tid % 3];
}

// Radial MLP + message + segmented scatter over receiver-sorted edges.
__global__ __launch_bounds__(256) void edge_mlp_k(
    const float* __restrict__ ef, const int* __restrict__ snd_s,
    const int* __restrict__ rcv_s,
    const float* __restrict__ w1, const float* __restrict__ b1,
    const float* __restrict__ w2, const float* __restrict__ scal,
    float* __restrict__ agg0, int layer, int E_)
{
    __shared__ __align__(16) char smem[18432];     // hsh(9216)+w2t(9216), aliased by ctile(16640)
    __shared__ float w1b[8 * 64 + 64];
    __shared__ int sndl[64], rcvl[64];
    unsigned short* hsh = (unsigned short*)smem;           // stride 72 shorts
    unsigned short* w2t = (unsigned short*)(smem + 9216);  // stride 72 shorts

    int t = threadIdx.x;
    int ebase = blockIdx.x * 64;

    if (t < 64) {
        sndl[t] = snd_s[ebase + t];
        rcvl[t] = rcv_s[ebase + t];
        w1b[512 + t] = b1[layer * FD + t];
    }
    for (int i = t; i < 512; i += 256) w1b[i] = w1[layer * 512 + i];
    #pragma unroll
    for (int i = 0; i < 16; ++i) {
        int linear = i * 256 + t;              // = k*64 + f
        int k = linear >> 6, f = linear & 63;
        w2t[f * 72 + k] = f2bf(w2[layer * 4096 + linear]);
    }
    __syncthreads();

    // phase 1: thread -> edge e = t&63, k-range kb..kb+15 (ef sorted: coalesced)
    {
        int e = t & 63, kb = (t >> 6) * 16;
        const f32x4* e4 = (const f32x4*)(ef + (size_t)(ebase + e) * NBES);
        f32x4 A0 = e4[0], A1 = e4[1];
        float efr[8] = {A0.x, A0.y, A0.z, A0.w, A1.x, A1.y, A1.z, A1.w};
        unsigned int hv[8];
        #pragma unroll
        for (int jp = 0; jp < 8; ++jp) {
            unsigned int pk = 0;
            #pragma unroll
            for (int half = 0; half < 2; ++half) {
                int k = kb + jp * 2 + half;
                float h = w1b[512 + k];
                #pragma unroll
                for (int i = 0; i < 8; ++i) h += efr[i] * w1b[i * 64 + k];
                pk |= ((unsigned int)f2bf(silu(h))) << (16 * half);
            }
            hv[jp] = pk;
        }
        uint4* dst = (uint4*)&hsh[e * 72 + kb];
        dst[0] = make_uint4(hv[0], hv[1], hv[2], hv[3]);
        dst[1] = make_uint4(hv[4], hv[5], hv[6], hv[7]);
    }
    __syncthreads();

    // phase 2: wave w -> edge rows 16w..16w+15, all 4 feature tiles
    int w = t >> 6, lane = t & 63;
    int mrow = lane & 15, quad = lane >> 4;
    short8 a0 = *(const short8*)&hsh[(16 * w + mrow) * 72 + quad * 8];
    short8 a1 = *(const short8*)&hsh[(16 * w + mrow) * 72 + 32 + quad * 8];
    f32x4 c[4];
    #pragma unroll
    for (int nt = 0; nt < 4; ++nt) {
        short8 b0 = *(const short8*)&w2t[(nt * 16 + mrow) * 72 + quad * 8];
        short8 bv = *(const short8*)&w2t[(nt * 16 + mrow) * 72 + 32 + quad * 8];
        f32x4 cc = {0.f, 0.f, 0.f, 0.f};
        cc = __builtin_amdgcn_mfma_f32_16x16x32_bf16(a0, b0, cc, 0, 0, 0);
        cc = __builtin_amdgcn_mfma_f32_16x16x32_bf16(a1, bv, cc, 0, 0, 0);
        c[nt] = cc;
    }
    __syncthreads();                                // hsh/w2t dead; alias as ctile
    float* ctile = (float*)smem;                    // 64 x 65
    #pragma unroll
    for (int nt = 0; nt < 4; ++nt)
        #pragma unroll
        for (int reg = 0; reg < 4; ++reg)
            ctile[(16 * w + quad * 4 + reg) * 65 + nt * 16 + mrow] = c[nt][reg];
    __syncthreads();

    // epilogue: wave w reduces sorted positions [16w,16w+16); receiver id wave-uniform
    int f = lane;
    int p0 = w * 16;
    int curR = rcvl[p0];
    float run = 0.f;
    #pragma unroll
    for (int pp = 0; pp < 16; ++pp) {
        int p = p0 + pp;
        int r = rcvl[p];
        float v = ctile[p * 65 + f] * scal[(size_t)sndl[p] * FD + f];
        if (r != curR) {
            atomicAdd(&agg0[(size_t)curR * FD + f], run);
            run = v; curR = r;
        } else {
            run += v;
        }
    }
    atomicAdd(&agg0[(size_t)curR * FD + f], run);
}

// Node update: scalars' = agg/16 + (agg/16)^2 + scal*prod_w[spec]; per-node energies to scratch.
__global__ __launch_bounds__(256) void node_update_k(
    float* __restrict__ scal, float* __restrict__ agg0,
    const int* __restrict__ spec, const float* __restrict__ prod_w,
    const float* __restrict__ readout_w, const float* __restrict__ ro2_w1,
    const float* __restrict__ ro2_b1, const float* __restrict__ ro2_w2,
    const float* __restrict__ charge_w, float* __restrict__ q,
    float* __restrict__ out_nodeE, float* __restrict__ nEl,
    int layer, int last, int N_)
{
    __shared__ float vsh[4][FD];
    int wid = threadIdx.x >> 6, lane = threadIdx.x & 63;
    int n = blockIdx.x * 4 + wid;
    int sp = spec[n];
    size_t idx = (size_t)n * FD + lane;
    float a = agg0[idx] * 0.0625f;
    agg0[idx] = 0.f;                       // pre-zero for next layer
    float v = a + a * a + scal[idx] * prod_w[(layer * NEL + sp) * FD + lane];
    scal[idx] = v;

    float ne;
    if (!last) {
        ne = wred(v * readout_w[layer * FD + lane]);
    } else {
        vsh[wid][lane] = v;
        __syncthreads();
        float h = 0.f;
        if (lane < HML) {
            h = ro2_b1[lane];
            for (int ff = 0; ff < FD; ++ff) h += vsh[wid][ff] * ro2_w1[ff * HML + lane];
            h = silu(h) * ro2_w2[lane];
        }
        ne = wred(h);
    }
    float qs = wred(v * charge_w[layer * FD + lane]);
    if (lane == 0) {
        nEl[n] = ne;
        out_nodeE[n] += ne;
        q[n] += qs;
    }
}

// Direct screened Coulomb: block = (graph, 64-wide i-chunk, 250-wide j-slice). 1280 blocks.
__global__ __launch_bounds__(256) void coulomb_k(
    const float* __restrict__ q, const float* __restrict__ pos,
    float* __restrict__ eel, int ng)
{
    __shared__ float qs[250], jx[250], jy[250], jz[250];
    __shared__ float wsum[4];
    int bid = blockIdx.x;
    int g = bid >> 6, rem = bid & 63;
    int ic = rem >> 2, jc = rem & 3;
    int tid = threadIdx.x, lane = tid & 63, w = tid >> 6;
    const float* qg = q + (size_t)g * ng;
    const float* pg = pos + (size_t)g * ng * 3;
    int jbase = jc * 250;
    if (tid < 250) {
        int j = jbase + tid;
        qs[tid] = qg[j];
        jx[tid] = pg[(size_t)j*3+0]; jy[tid] = pg[(size_t)j*3+1]; jz[tid] = pg[(size_t)j*3+2];
    }
    __syncthreads();
    int i = ic * 64 + lane;
    float acc = 0.f;
    if (i < ng) {
        float qi = qg[i];
        float xi = pg[(size_t)i*3+0], yi = pg[(size_t)i*3+1], zi = pg[(size_t)i*3+2];
        for (int jj = w; jj < 250; jj += 4) {     // jj wave-uniform -> LDS broadcast
            int j = jbase + jj;
            float dx = xi - jx[jj], dy = yi - jy[jj], dz = zi - jz[jj];
            float d2 = dx*dx + dy*dy + dz*dz + 1e-12f;
            float rinv = __frsqrt_rn(d2);
            float r = d2 * rinv;
            float x = 0.5f * r;
            float tt = __frcp_rn(1.f + 0.3275911f * x);
            float poly = ((((1.061405429f*tt - 1.453152027f)*tt + 1.421413741f)*tt
                           - 0.284496736f)*tt + 0.254829592f)*tt;
            float erfv = 1.f - poly * __expf(-x * x);
            float kern = (j == i) ? 0.f : erfv * rinv;
            acc += qi * qs[jj] * kern;
        }
    }
    acc = wred(acc);
    if (lane == 0) wsum[w] = acc;
    __syncthreads();
    if (tid == 0) atomicAdd(&eel[g], 0.5f * (wsum[0] + wsum[1] + wsum[2] + wsum[3]));
}

// Per-graph reductions + final output assembly (runs after coulomb).
__global__ __launch_bounds__(256) void graph_final_k(
    const int* __restrict__ spec, const float* __restrict__ ae,
    const float* __restrict__ fc, const float* __restrict__ pos,
    const float* __restrict__ q, const float* __restrict__ nE0,
    const float* __restrict__ nE1, const float* __restrict__ polpart,
    const float* __restrict__ eel, float* __restrict__ out,
    int ng, int N_)
{
    __shared__ float red[4][8];
    __shared__ float res[7];
    int g = blockIdx.x;
    int tid = threadIdx.x, wid = tid >> 6, lane = tid & 63;
    float se0 = 0.f, s0 = 0.f, s1 = 0.f, sq = 0.f, p0 = 0.f, p1 = 0.f, p2 = 0.f;
    for (int n = g * ng + tid; n < (g + 1) * ng; n += 256) {
        int sp = spec[n];
        float fq = fc[sp];
        se0 += ae[sp];
        s0 += nE0[n];
        s1 += nE1[n];
        sq += q[n];
        p0 += fq * pos[(size_t)n*3+0];
        p1 += fq * pos[(size_t)n*3+1];
        p2 += fq * pos[(size_t)n*3+2];
    }
    float vals[7] = {se0, s0, s1, sq, p0, p1, p2};
    #pragma unroll
    for (int k = 0; k < 7; ++k) {
        float r = wred(vals[k]);
        if (lane == 0) red[wid][k] = r;
    }
    __syncthreads();
    if (tid < 7) {
        float s = red[0][tid] + red[1][tid] + red[2][tid] + red[3][tid];
        if (tid >= 4) {
            int cdim = tid - 4;
            for (int b = 0; b < EGB; ++b) s += polpart[b * (GG * 3) + g * 3 + cdim];
        }
        res[tid] = s;
    }
    __syncthreads();
    if (tid == 0) {
        int G_ = GG;
        float a0 = res[0], a1 = res[1], a2 = res[2];
        out[g] = a0 + a1 + a2 + eel[g];             // total_energy
        float* contrib = out + G_ + N_;             // contributions [G,3]
        contrib[g*3+0] = a0; contrib[g*3+1] = a1; contrib[g*3+2] = a2;
        float* pol = contrib + G_ * 3;              // pol [G,3]
        pol[g*3+0] = res[4]; pol[g*3+1] = res[5]; pol[g*3+2] = res[6];
        float* qt = pol + G_ * 3;                   // total_charge [G]
        qt[g] = res[3];
    }
}

extern "C" void kernel_launch(void* const* d_in, const int* in_sizes, int n_in,
                              void* d_out, int out_size, void* d_ws, size_t ws_size,
                              hipStream_t stream)
{
    const float* node_attrs      = (const float*)d_in[0];
    const float* positions       = (const float*)d_in[1];
    const int*   edge_index      = (const int*)d_in[2];
    const float* atomic_energies = (const float*)d_in[5];
    const float* embed_w         = (const float*)d_in[6];
    const float* radial_w1       = (const float*)d_in[7];
    const float* radial_b1       = (const float*)d_in[8];
    const float* radial_w2       = (const float*)d_in[9];
    const float* prod_w          = (const float*)d_in[10];
    const float* readout_w       = (const float*)d_in[11];
    const float* ro2_w1          = (const float*)d_in[12];
    const float* ro2_b1          = (const float*)d_in[13];
    const float* ro2_w2          = (const float*)d_in[14];
    const float* charge_w        = (const float*)d_in[15];
    const float* flux_w          = (const float*)d_in[16];
    const float* formal_charges  = (const float*)d_in[17];

    int N = in_sizes[0] / NEL;     // 20000
    int E = in_sizes[2] / 2;       // 320000
    const int G_ = GG;             // 20
    int ng = N / G_;               // 1000

    float* ws      = (float*)d_ws;
    float* scal    = ws;                               // [N,64]
    float* agg0    = scal + (size_t)N * FD;            // [N,64]
    float* ef      = agg0 + (size_t)N * FD;            // [E,8] (sorted order)
    float* q       = ef + (size_t)E * NBES;            // [N]
    int*   spec    = (int*)(q + N);                    // [N]
    float* nE0     = (float*)(spec + N);               // [N]
    float* nE1     = nE0 + N;                          // [N]
    float* polpart = nE1 + N;                          // [EGB*60]
    int*   cnt     = (int*)(polpart + EGB * (GG * 3)); // [N]
    float* acc     = (float*)(cnt + N);                // [160] (contiguous w/ cnt for 1 memset)
    int*   cur     = (int*)(acc + 160);                // [N]
    int*   snd_s   = cur + N;                          // [E]
    int*   rcv_s   = snd_s + E;                        // [E]

    float* out = (float*)d_out;
    float* out_nodeE = out + G_;

    hipMemsetAsync(agg0, 0, (size_t)N * FD * sizeof(float), stream);
    hipMemsetAsync(cnt, 0, (size_t)N * sizeof(int) + 160 * sizeof(float), stream);

    setup_k<<<(N * FD) / 256, 256, 0, stream>>>(
        node_attrs, atomic_energies, formal_charges, embed_w, edge_index,
        spec, q, out_nodeE, scal, cnt, N, E);
    scan_k<<<1, 1024, 0, stream>>>(cnt, cur, N);
    scatter_k<<<(E + 255) / 256, 256, 0, stream>>>(edge_index, cur, snd_s, rcv_s, E);

    edge_geom_k<<<EGB, 256, 0, stream>>>(positions, snd_s, rcv_s, flux_w, ef, polpart, E, ng);

    for (int l = 0; l < 2; ++l) {
        edge_mlp_k<<<E / 64, 256, 0, stream>>>(
            ef, snd_s, rcv_s, radial_w1, radial_b1, radial_w2, scal, agg0, l, E);
        node_update_k<<<N / 4, 256, 0, stream>>>(
            scal, agg0, spec, prod_w, readout_w, ro2_w1, ro2_b1, ro2_w2,
            charge_w, q, out_nodeE, (l == 0) ? nE0 : nE1,
            l, (l == 1) ? 1 : 0, N);
    }

    coulomb_k<<<G_ * 64, 256, 0, stream>>>(q, positions, acc + 60, ng);
    graph_final_k<<<G_, 256, 0, stream>>>(spec, atomic_energies, formal_charges,
                                          positions, q, nE0, nE1, polpart,
                                          acc + 60, out, ng, N);
}